// Round 1
// 67.876 us; speedup vs baseline: 1.1764x; 1.1764x over previous
//
#include <hip/hip_runtime.h>
#include <math.h>

// AGCRNCellWithMLP, N=4096, IN=64, QD=16, CI=129. All tensors fp32.
// nodes_ind == arange(N) -> identity indexing.
// Split-bf16 MFMA 32x32x16 (a = a_hi + a_lo; D += ah*bh + al*bh + ah*bl).
// Pipeline (3 kernels): k0 pack -> k1 adj@C split-K -> k23 fused
// (P1 reduce + r/u MLP + h2 + cand MLP + out), removing k1b/k2/k3 chain,
// XV/U/H2 intermediates, and duplicated staging.

#define NN   4096
#define XCC  65
#define HCC  64
#define QDIM 16
#define CI   129
#define CST  132     // fp32 combined row stride
#define AKST 520     // u16 per kst sub-block in k23 LDS: 64 lanes*8 + 8 pad
#define GSTRIDE 147456  // u16 per gate in packed W: 16d*2ct*9kst*64lane*8

typedef unsigned short u16;
typedef __attribute__((ext_vector_type(4))) unsigned short ushort4_t;
typedef __attribute__((ext_vector_type(8))) unsigned short ushort8_t;
typedef __attribute__((ext_vector_type(8))) short bf16x8;
typedef __attribute__((ext_vector_type(16))) float f32x16;

__device__ __forceinline__ void split2(float a, u16& hi, u16& lo) {
  unsigned u = __float_as_uint(a);
  hi = (u16)(u >> 16);                          // truncated high part
  float rec = __uint_as_float(u & 0xFFFF0000u);
  float lf = a - rec;                           // exact residual
  unsigned v = __float_as_uint(lf);
  v += 0x7FFF + ((v >> 16) & 1);                // RNE low part
  lo = (u16)(v >> 16);
}

__device__ __forceinline__ void gload_lds16(const void* gsrc, void* ldst) {
  __builtin_amdgcn_global_load_lds(
      (const __attribute__((address_space(1))) unsigned int*)gsrc,
      (__attribute__((address_space(3))) unsigned int*)ldst, 16, 0, 0);
}

// ---------------- K0: merged pack of B=[x|h] and W_r/W_u/W_c ----------------
__global__ __launch_bounds__(256) void k0_pack(const float* __restrict__ x,
                                               const float* __restrict__ h,
                                               u16* __restrict__ Bh,
                                               u16* __restrict__ Bl,
                                               const float* __restrict__ Wr,
                                               const float* __restrict__ Wu,
                                               const float* __restrict__ Wc,
                                               u16* __restrict__ Wh,
                                               u16* __restrict__ Wl) {
  __shared__ float sT[64][161];
  const int t = threadIdx.x;
  if (blockIdx.x < 64) {
    const int n0 = blockIdx.x * 64;
    for (int f = t; f < 64 * XCC; f += 256) {
      int n = f / XCC, c = f - n * XCC;
      sT[n][c] = x[(size_t)(n0 + n) * XCC + c];
    }
    for (int f = t; f < 64 * HCC; f += 256) {
      int n = f >> 6, c = f & 63;
      sT[n][XCC + c] = h[(size_t)(n0 + n) * HCC + c];
    }
    for (int f = t; f < 64 * 31; f += 256) {
      int n = f / 31, c = f - n * 31;
      sT[n][CI + c] = 0.f;
    }
    __syncthreads();
    for (int idx = t; idx < 5 * 4 * 64; idx += 256) {
      const int lane = idx & 63;
      const int ksl = (idx >> 6) & 3;
      const int ct = idx >> 8;
      const int nl = ksl * 16 + (lane >> 5) * 8;
      const int feat = ct * 32 + (lane & 31);
      ushort8_t vh, vl;
#pragma unroll
      for (int j = 0; j < 8; ++j) {
        u16 hi, lo; split2(sT[nl + j][feat], hi, lo);
        vh[j] = hi; vl[j] = lo;
      }
      const size_t off = (((size_t)ct * 256 + (blockIdx.x * 4) + ksl) * 64 + lane) * 8;
      *(ushort8_t*)(Bh + off) = vh;
      *(ushort8_t*)(Bl + off) = vl;
    }
  } else {
    int gid = (blockIdx.x - 64) * 256 + t;
    if (gid >= 3 * 16 * 2 * 9 * 64) return;
    int lane = gid & 63;
    int rest = gid >> 6;
    int kst = rest % 9; rest /= 9;
    int ct = rest & 1; rest >>= 1;
    int d = rest & 15; rest >>= 4;
    const float* W = (rest == 0) ? Wr : (rest == 1 ? Wu : Wc);
    const int o = ct * 32 + (lane & 31);
    const int i0 = kst * 16 + (lane >> 5) * 8;
    ushort8_t vh, vl;
#pragma unroll
    for (int j = 0; j < 8; ++j) {
      int i = i0 + j;
      float v = (i < CI) ? W[((size_t)d * CI + i) * 64 + o] : 0.f;
      u16 hi, lo; split2(v, hi, lo);
      vh[j] = hi; vl[j] = lo;
    }
    const size_t off = (size_t)gid * 8;
    *(ushort8_t*)(Wh + off) = vh;
    *(ushort8_t*)(Wl + off) = vl;
  }
}

// ---------------- K1: P1[sp] = adj @ C via MFMA -----------------------------
// grid (64, SPK), 256 thr = 4 waves: rgrp=w&1 (32 rows), cthalf=w>>1
// (ctiles 0-2 / 3-4). K-step 16, fine-grained deep pipeline.
template <int SPK>
__global__ __launch_bounds__(256, 4) void k1_mfma(const float* __restrict__ adj,
                                                  const u16* __restrict__ Bh,
                                                  const u16* __restrict__ Bl,
                                                  float* __restrict__ P1) {
  constexpr int KLEN = 4096 / SPK;         // 256 @ SPK=16
  constexpr int STEPS = KLEN / 16;         // 16
  __shared__ u16 sAh[2][2][64][8];         // [abuf][rgrp][lane][8]  4 KB
  __shared__ u16 sAl[2][2][64][8];         // 4 KB
  __shared__ u16 sB[3][10][512];           // [bbuf][chunk ct*2+hl][1KB] 30 KB
  __shared__ u16 sScratch[512];            // dummy DMA target 1 KB
  const int t = threadIdx.x;
  const int lane = t & 63;
  const int w = t >> 6;
  const int rgrp = w & 1;
  const int cthalf = w >> 1;
  const int m0 = blockIdx.x * 64;
  const int sp = blockIdx.y;
  const int ct0 = cthalf ? 3 : 0;
  const int R = t >> 2;                    // staging row 0..63
  const int ksts = t & 3;                  // k-quad within step
  const int srg = R >> 5, srl = R & 31;
  const int skh = ksts >> 1, sj0 = (ksts & 1) * 4;

  f32x16 a0, a1, a2;
#pragma unroll
  for (int r = 0; r < 16; ++r) { a0[r] = 0.f; a1[r] = 0.f; a2[r] = 0.f; }

  const float* aptr = adj + (size_t)(m0 + R) * NN + sp * KLEN + ksts * 4;
  float4 va, vb, vc;                       // 3-deep A register sets

#define LOADA(it, tgt) tgt = *(const float4*)(aptr + (it) * 16);

#define CONV4(src, abuf)                                                       \
  {                                                                            \
    u16 h0, h1, h2, h3, l0, l1, l2, l3;                                        \
    split2(src.x, h0, l0); split2(src.y, h1, l1);                              \
    split2(src.z, h2, l2); split2(src.w, h3, l3);                              \
    ushort4_t hv = {h0, h1, h2, h3};                                           \
    ushort4_t lv = {l0, l1, l2, l3};                                           \
    *(ushort4_t*)&sAh[abuf][srg][srl + 32 * skh][sj0] = hv;                    \
    *(ushort4_t*)&sAl[abuf][srg][srl + 32 * skh][sj0] = lv;                    \
  }

#define BDMA(it, bbuf)                                                         \
  {                                                                            \
    _Pragma("unroll")                                                          \
    for (int j = 0; j < 3; ++j) {                                              \
      const int c = w + 4 * j;                                                 \
      const int ct = (c < 10) ? (c >> 1) : 0;                                  \
      const int hl = (c < 10) ? (c & 1) : 0;                                   \
      const int ks = sp * STEPS + (it);                                        \
      const u16* src =                                                         \
          (hl ? Bl : Bh) + (((size_t)ct * 256 + ks) * 64 + lane) * 8;          \
      gload_lds16(src, (c < 10) ? &sB[bbuf][c][0] : &sScratch[0]);             \
    }                                                                          \
  }

#define BAR(N)                                                                 \
  asm volatile("s_waitcnt vmcnt(" #N ") lgkmcnt(0)" ::: "memory");             \
  __builtin_amdgcn_sched_barrier(0);                                           \
  __builtin_amdgcn_s_barrier();                                                \
  __builtin_amdgcn_sched_barrier(0);

#define COMPUTE(abuf, bbuf)                                                    \
  {                                                                            \
    bf16x8 ah = *(const bf16x8*)&sAh[abuf][rgrp][lane][0];                     \
    bf16x8 al = *(const bf16x8*)&sAl[abuf][rgrp][lane][0];                     \
    const int cb = ct0 * 2;                                                    \
    bf16x8 b0h = *(const bf16x8*)&sB[bbuf][cb + 0][lane * 8];                  \
    bf16x8 b0l = *(const bf16x8*)&sB[bbuf][cb + 1][lane * 8];                  \
    bf16x8 b1h = *(const bf16x8*)&sB[bbuf][cb + 2][lane * 8];                  \
    bf16x8 b1l = *(const bf16x8*)&sB[bbuf][cb + 3][lane * 8];                  \
    a0 = __builtin_amdgcn_mfma_f32_32x32x16_bf16(ah, b0h, a0, 0, 0, 0);        \
    a1 = __builtin_amdgcn_mfma_f32_32x32x16_bf16(ah, b1h, a1, 0, 0, 0);        \
    a0 = __builtin_amdgcn_mfma_f32_32x32x16_bf16(al, b0h, a0, 0, 0, 0);        \
    a1 = __builtin_amdgcn_mfma_f32_32x32x16_bf16(al, b1h, a1, 0, 0, 0);        \
    a0 = __builtin_amdgcn_mfma_f32_32x32x16_bf16(ah, b0l, a0, 0, 0, 0);        \
    a1 = __builtin_amdgcn_mfma_f32_32x32x16_bf16(ah, b1l, a1, 0, 0, 0);        \
    if (cthalf == 0) {                                                         \
      bf16x8 b2h = *(const bf16x8*)&sB[bbuf][cb + 4][lane * 8];                \
      bf16x8 b2l = *(const bf16x8*)&sB[bbuf][cb + 5][lane * 8];                \
      a2 = __builtin_amdgcn_mfma_f32_32x32x16_bf16(ah, b2h, a2, 0, 0, 0);      \
      a2 = __builtin_amdgcn_mfma_f32_32x32x16_bf16(al, b2h, a2, 0, 0, 0);      \
      a2 = __builtin_amdgcn_mfma_f32_32x32x16_bf16(ah, b2l, a2, 0, 0, 0);      \
    }                                                                          \
  }

  // prologue: A0,A1,A2 in regs; B0,B1 DMA'd; convert A0; drain B0 only.
  LOADA(0, va);
  BDMA(0, 0);
  LOADA(1, vb);
  BDMA(1, 1);
  LOADA(2, vc);
  CONV4(va, 0);
  BAR(5)   // retire B0 (3); keep vb, B1(3), vc
#pragma unroll
  for (int it = 0; it < STEPS; ++it) {
    const int abuf = it & 1;
    const int bbuf = it % 3;
    if (it < STEPS - 2) BDMA(it + 2, (it + 2) % 3);
    if (it <= STEPS - 4) {
      if ((it % 3) == 0) { LOADA(it + 3, va); }
      else if ((it % 3) == 1) { LOADA(it + 3, vb); }
      else { LOADA(it + 3, vc); }
    }
    COMPUTE(abuf, bbuf);
    if (it < STEPS - 1) {
      if (((it + 1) % 3) == 0) { CONV4(va, abuf ^ 1); }
      else if (((it + 1) % 3) == 1) { CONV4(vb, abuf ^ 1); }
      else { CONV4(vc, abuf ^ 1); }
    }
    if (it <= STEPS - 4) { BAR(5) }
    else if (it == STEPS - 3) { BAR(4) }
    else if (it == STEPS - 2) { BAR(0) }
  }
#undef LOADA
#undef CONV4
#undef BDMA
#undef BAR
#undef COMPUTE
  // epilogue: C/D layout col=lane&31, row=(r&3)+8*(r>>2)+4*(lane>>5)
  float* outp = P1 + (size_t)sp * NN * CST;
  const int colb = lane & 31;
  const int rbase = m0 + rgrp * 32 + 4 * (lane >> 5);
  {
    const int colg = ct0 * 32 + colb;
#pragma unroll
    for (int r = 0; r < 16; ++r)
      outp[(size_t)(rbase + (r & 3) + 8 * (r >> 2)) * CST + colg] = a0[r];
  }
  {
    const int colg = (ct0 + 1) * 32 + colb;
    if (colg < CST) {
#pragma unroll
      for (int r = 0; r < 16; ++r)
        outp[(size_t)(rbase + (r & 3) + 8 * (r >> 2)) * CST + colg] = a1[r];
    }
  }
  if (cthalf == 0) {
    const int colg = 64 + colb;
#pragma unroll
    for (int r = 0; r < 16; ++r)
      outp[(size_t)(rbase + (r & 3) + 8 * (r >> 2)) * CST + colg] = a2[r];
  }
}

// ---------------- K23: fused P1-reduce + r,u + h2 + cand + out --------------
// grid (128, 2): x = 32-node block, y = own output ct half.
// Computes r for BOTH ct halves (needed to build full h2 locally), u and
// cand for own half only. All 8 waves work in every phase; wave dh owns
// accumulator rows {2dh, 2dh+1} after the sXfer exchange.

#define PACKA()                                                                \
  for (int s = t; s < 9 * 64; s += 512) {                                      \
    int kst = s >> 6, l = s & 63;                                              \
    int row = l & 31, k0i = kst * 16 + (l >> 5) * 8;                           \
    ushort8_t vh, vl;                                                          \
    _Pragma("unroll")                                                          \
    for (int j = 0; j < 8; ++j) {                                              \
      u16 hi, lo; split2(sXV[row][k0i + j], hi, lo);                           \
      vh[j] = hi; vl[j] = lo;                                                  \
    }                                                                          \
    *(ushort8_t*)&sAh[kst * AKST + l * 8] = vh;                                \
    *(ushort8_t*)&sAl[kst * AKST + l * 8] = vl;                                \
  }

template <int SPK>
__global__ __launch_bounds__(512) void k23_fused(
    const float* __restrict__ P1, const float* __restrict__ x,
    const float* __restrict__ h, const float* __restrict__ q,
    const u16* __restrict__ Wh, const u16* __restrict__ Wl,
    const float* __restrict__ br, const float* __restrict__ bu,
    const float* __restrict__ bc, float* __restrict__ out) {
  __shared__ float sXV[32][144];
  __shared__ u16 sAh[9 * AKST], sAl[9 * AKST];
  __shared__ float sQ[32][16];
  __shared__ float sXfer[8][16][64];
  const int t = threadIdx.x;
  const int n0 = blockIdx.x * 32;
  const int cto = blockIdx.y;
  // --- split-K reduce of P1 directly into sXV (replaces k1b + XV) ---
  for (int f = t; f < 32 * 33; f += 512) {
    int n = f / 33, c4 = f - n * 33;
    const float* p = P1 + (size_t)(n0 + n) * CST + c4 * 4;
    float sx = 0.f, sy = 0.f, sz = 0.f, sw = 0.f;
#pragma unroll
    for (int sp = 0; sp < SPK; ++sp) {
      float4 v = *(const float4*)(p + (size_t)sp * NN * CST);
      sx += v.x; sy += v.y; sz += v.z; sw += v.w;
    }
    sXV[n][c4 * 4 + 0] = sx; sXV[n][c4 * 4 + 1] = sy;
    sXV[n][c4 * 4 + 2] = sz; sXV[n][c4 * 4 + 3] = sw;
  }
  for (int f = t; f < 32 * 3; f += 512) {
    float4 z = {0, 0, 0, 0};
    *(float4*)&sXV[f / 3][132 + (f % 3) * 4] = z;
  }
  sQ[t >> 4][t & 15] = q[(size_t)(n0 + (t >> 4)) * QDIM + (t & 15)];
  __syncthreads();
  PACKA();
  __syncthreads();
  // stage x into sXV[.][0..64] now (only consumed by the second PACKA,
  // which is barrier-protected); hides the global latency under MFMA.
  for (int f = t; f < 32 * 65; f += 512) {
    int n = f / 65, i = f - n * 65;
    sXV[n][i] = x[(size_t)(n0 + n) * XCC + i];
  }
  const int lane = t & 63, dh = t >> 6;

  auto mfma_target = [&](const u16* gh, const u16* gl, int ct_sel,
                         float& o0, float& o1) {
    f32x16 acc;
#pragma unroll
    for (int r = 0; r < 16; ++r) acc[r] = 0.f;
#pragma unroll
    for (int dd = 0; dd < 2; ++dd) {
      const int d = dh * 2 + dd;
      const size_t bb = (((size_t)d * 2 + ct_sel) * 9 * 64 + lane) * 8;
      f32x16 t0, t1, t2;
#pragma unroll
      for (int r = 0; r < 16; ++r) { t0[r] = 0.f; t1[r] = 0.f; t2[r] = 0.f; }
#pragma unroll
      for (int kst = 0; kst < 9; ++kst) {
        bf16x8 ah = *(const bf16x8*)&sAh[kst * AKST + lane * 8];
        bf16x8 al = *(const bf16x8*)&sAl[kst * AKST + lane * 8];
        bf16x8 bh = *(const bf16x8*)(gh + bb + kst * 512);
        bf16x8 bl = *(const bf16x8*)(gl + bb + kst * 512);
        t0 = __builtin_amdgcn_mfma_f32_32x32x16_bf16(ah, bh, t0, 0, 0, 0);
        t1 = __builtin_amdgcn_mfma_f32_32x32x16_bf16(al, bh, t1, 0, 0, 0);
        t2 = __builtin_amdgcn_mfma_f32_32x32x16_bf16(ah, bl, t2, 0, 0, 0);
      }
#pragma unroll
      for (int r = 0; r < 16; ++r) {
        int node = (r & 3) + 8 * (r >> 2) + 4 * (lane >> 5);
        acc[r] += sQ[node][d] * (t0[r] + t1[r] + t2[r]);
      }
    }
    __syncthreads();   // previous sXfer round fully consumed
#pragma unroll
    for (int r = 0; r < 16; ++r) sXfer[dh][r][lane] = acc[r];
    __syncthreads();
    const int rr0 = dh * 2, rr1 = dh * 2 + 1;
    float s0 = 0.f, s1 = 0.f;
#pragma unroll
    for (int wv = 0; wv < 8; ++wv) {
      s0 += sXfer[wv][rr0][lane];
      s1 += sXfer[wv][rr1][lane];
    }
    o0 = s0; o1 = s1;
  };

  auto add_bias = [&](const float* bias, int node, int col, float pre) {
#pragma unroll
    for (int d = 0; d < 16; ++d) pre += sQ[node][d] * bias[(size_t)d * 64 + col];
    return pre;
  };

  float r0p0, r0p1, r1p0, r1p1, up0, up1;
  mfma_target(Wh, Wl, 0, r0p0, r0p1);                           // r, cols 0..31
  mfma_target(Wh, Wl, 1, r1p0, r1p1);                           // r, cols 32..63
  mfma_target(Wh + GSTRIDE, Wl + GSTRIDE, cto, up0, up1);       // u, own half

  const int col0 = lane & 31, col1 = 32 + col0, colu = cto * 32 + col0;
  float uval[2], h2own[2];
#pragma unroll
  for (int i = 0; i < 2; ++i) {
    const int rr = dh * 2 + i;
    const int node = (rr & 3) + 8 * (rr >> 2) + 4 * (lane >> 5);
    float pr0 = add_bias(br, node, col0, i ? r0p1 : r0p0);
    float pr1 = add_bias(br, node, col1, i ? r1p1 : r1p0);
    float pu  = add_bias(bu, node, colu, i ? up1 : up0);
    float rg0 = 1.f / (1.f + expf(-pr0));
    float rg1 = 1.f / (1.f + expf(-pr1));
    uval[i] = 1.f / (1.f + expf(-pu));
    float h2a = rg0 * h[(size_t)(n0 + node) * HCC + col0];
    float h2b = rg1 * h[(size_t)(n0 + node) * HCC + col1];
    sXV[node][XCC + col0] = h2a;   // build full h2 row locally
    sXV[node][XCC + col1] = h2b;
    h2own[i] = cto ? h2b : h2a;
  }
  __syncthreads();   // x-stage + h2 writes complete; sXfer reads done
  PACKA();           // repack A = [x | h2] (cols 129..143 still zero)
  __syncthreads();
  float cp0, cp1;
  mfma_target(Wh + 2 * GSTRIDE, Wl + 2 * GSTRIDE, cto, cp0, cp1);
#pragma unroll
  for (int i = 0; i < 2; ++i) {
    const int rr = dh * 2 + i;
    const int node = (rr & 3) + 8 * (rr >> 2) + 4 * (lane >> 5);
    float pc = add_bias(bc, node, colu, i ? cp1 : cp0);
    float cand = tanhf(pc);
    out[(size_t)(n0 + node) * HCC + colu] =
        (1.f - uval[i]) * h2own[i] + uval[i] * cand;
  }
}

extern "C" void kernel_launch(void* const* d_in, const int* in_sizes, int n_in,
                              void* d_out, int out_size, void* d_ws, size_t ws_size,
                              hipStream_t stream) {
  const float* x   = (const float*)d_in[0];
  const float* h   = (const float*)d_in[1];
  const float* q   = (const float*)d_in[2];
  const float* adj = (const float*)d_in[3];
  const float* Wr  = (const float*)d_in[5];
  const float* br  = (const float*)d_in[6];
  const float* Wu  = (const float*)d_in[7];
  const float* bu  = (const float*)d_in[8];
  const float* Wc  = (const float*)d_in[9];
  const float* bc  = (const float*)d_in[10];
  float* out = (float*)d_out;

  const size_t NEED16 = (size_t)16 * NN * CST * 4 + 2162688 + 10485760 + 1769472;
  const int spk = (ws_size >= NEED16) ? 16 : 8;

  char* ws = (char*)d_ws;
  const size_t OFF_P1 = 0;
  const size_t OFF_XV = OFF_P1 + (size_t)spk * NN * CST * 4;  // region kept for layout
  const size_t OFF_BP = OFF_XV + (size_t)NN * CST * 4;
  const size_t OFF_WH = OFF_BP + (size_t)2 * 5 * 256 * 64 * 8 * 2;
  const size_t OFF_WL = OFF_WH + (size_t)3 * GSTRIDE * 2;
  float* P1 = (float*)(ws + OFF_P1);
  u16*   Bh = (u16*)(ws + OFF_BP);
  u16*   Bl = (u16*)(ws + OFF_BP + (size_t)5 * 256 * 64 * 8 * 2);
  u16*   Wh = (u16*)(ws + OFF_WH);
  u16*   Wl = (u16*)(ws + OFF_WL);

  hipLaunchKernelGGL(k0_pack, dim3(280), dim3(256), 0, stream,
                     x, h, Bh, Bl, Wr, Wu, Wc, Wh, Wl);
  if (spk == 16) {
    hipLaunchKernelGGL(k1_mfma<16>, dim3(64, 16), dim3(256), 0, stream, adj, Bh, Bl, P1);
    hipLaunchKernelGGL(k23_fused<16>, dim3(128, 2), dim3(512), 0, stream,
                       P1, x, h, q, Wh, Wl, br, bu, bc, out);
  } else {
    hipLaunchKernelGGL(k1_mfma<8>, dim3(64, 8), dim3(256), 0, stream, adj, Bh, Bl, P1);
    hipLaunchKernelGGL(k23_fused<8>, dim3(128, 2), dim3(512), 0, stream,
                       P1, x, h, q, Wh, Wl, br, bu, bc, out);
  }
}

// Round 2
// 64.432 us; speedup vs baseline: 1.2392x; 1.0534x over previous
//
#include <hip/hip_runtime.h>
#include <math.h>

// AGCRNCellWithMLP, N=4096, IN=64, QD=16, CI=129. All tensors fp32.
// nodes_ind == arange(N) -> identity indexing.
// Split-bf16 MFMA 32x32x16 (a = a_hi + a_lo; D += ah*bh + al*bh + ah*bl).
// Pipeline (3 kernels): k0 pack -> k1 adj@C split-K -> k23 fused.
// R1 change: k23 fuses the three independent targets (r ct0, r ct1, u) into
// ONE MFMA phase (3 accumulator chains, 6 outstanding W loads per K-step),
// single widened sXfer exchange; syncthreads 12 -> 6. sXV stride padded
// 144 -> 148 to break the 16-way PACKA bank conflict.

#define NN   4096
#define XCC  65
#define HCC  64
#define QDIM 16
#define CI   129
#define CST  132     // fp32 combined row stride
#define AKST 520     // u16 per kst sub-block in k23 LDS: 64 lanes*8 + 8 pad
#define XVST 148     // padded sXV row stride (words); 148%32=20 -> 4-way max
#define GSTRIDE 147456  // u16 per gate in packed W: 16d*2ct*9kst*64lane*8

typedef unsigned short u16;
typedef __attribute__((ext_vector_type(4))) unsigned short ushort4_t;
typedef __attribute__((ext_vector_type(8))) unsigned short ushort8_t;
typedef __attribute__((ext_vector_type(8))) short bf16x8;
typedef __attribute__((ext_vector_type(16))) float f32x16;

__device__ __forceinline__ void split2(float a, u16& hi, u16& lo) {
  unsigned u = __float_as_uint(a);
  hi = (u16)(u >> 16);                          // truncated high part
  float rec = __uint_as_float(u & 0xFFFF0000u);
  float lf = a - rec;                           // exact residual
  unsigned v = __float_as_uint(lf);
  v += 0x7FFF + ((v >> 16) & 1);                // RNE low part
  lo = (u16)(v >> 16);
}

__device__ __forceinline__ void gload_lds16(const void* gsrc, void* ldst) {
  __builtin_amdgcn_global_load_lds(
      (const __attribute__((address_space(1))) unsigned int*)gsrc,
      (__attribute__((address_space(3))) unsigned int*)ldst, 16, 0, 0);
}

// ---------------- K0: merged pack of B=[x|h] and W_r/W_u/W_c ----------------
__global__ __launch_bounds__(256) void k0_pack(const float* __restrict__ x,
                                               const float* __restrict__ h,
                                               u16* __restrict__ Bh,
                                               u16* __restrict__ Bl,
                                               const float* __restrict__ Wr,
                                               const float* __restrict__ Wu,
                                               const float* __restrict__ Wc,
                                               u16* __restrict__ Wh,
                                               u16* __restrict__ Wl) {
  __shared__ float sT[64][161];
  const int t = threadIdx.x;
  if (blockIdx.x < 64) {
    const int n0 = blockIdx.x * 64;
    for (int f = t; f < 64 * XCC; f += 256) {
      int n = f / XCC, c = f - n * XCC;
      sT[n][c] = x[(size_t)(n0 + n) * XCC + c];
    }
    for (int f = t; f < 64 * HCC; f += 256) {
      int n = f >> 6, c = f & 63;
      sT[n][XCC + c] = h[(size_t)(n0 + n) * HCC + c];
    }
    for (int f = t; f < 64 * 31; f += 256) {
      int n = f / 31, c = f - n * 31;
      sT[n][CI + c] = 0.f;
    }
    __syncthreads();
    for (int idx = t; idx < 5 * 4 * 64; idx += 256) {
      const int lane = idx & 63;
      const int ksl = (idx >> 6) & 3;
      const int ct = idx >> 8;
      const int nl = ksl * 16 + (lane >> 5) * 8;
      const int feat = ct * 32 + (lane & 31);
      ushort8_t vh, vl;
#pragma unroll
      for (int j = 0; j < 8; ++j) {
        u16 hi, lo; split2(sT[nl + j][feat], hi, lo);
        vh[j] = hi; vl[j] = lo;
      }
      const size_t off = (((size_t)ct * 256 + (blockIdx.x * 4) + ksl) * 64 + lane) * 8;
      *(ushort8_t*)(Bh + off) = vh;
      *(ushort8_t*)(Bl + off) = vl;
    }
  } else {
    int gid = (blockIdx.x - 64) * 256 + t;
    if (gid >= 3 * 16 * 2 * 9 * 64) return;
    int lane = gid & 63;
    int rest = gid >> 6;
    int kst = rest % 9; rest /= 9;
    int ct = rest & 1; rest >>= 1;
    int d = rest & 15; rest >>= 4;
    const float* W = (rest == 0) ? Wr : (rest == 1 ? Wu : Wc);
    const int o = ct * 32 + (lane & 31);
    const int i0 = kst * 16 + (lane >> 5) * 8;
    ushort8_t vh, vl;
#pragma unroll
    for (int j = 0; j < 8; ++j) {
      int i = i0 + j;
      float v = (i < CI) ? W[((size_t)d * CI + i) * 64 + o] : 0.f;
      u16 hi, lo; split2(v, hi, lo);
      vh[j] = hi; vl[j] = lo;
    }
    const size_t off = (size_t)gid * 8;
    *(ushort8_t*)(Wh + off) = vh;
    *(ushort8_t*)(Wl + off) = vl;
  }
}

// ---------------- K1: P1[sp] = adj @ C via MFMA -----------------------------
// grid (64, SPK), 256 thr = 4 waves: rgrp=w&1 (32 rows), cthalf=w>>1
// (ctiles 0-2 / 3-4). K-step 16, fine-grained deep pipeline.
template <int SPK>
__global__ __launch_bounds__(256, 4) void k1_mfma(const float* __restrict__ adj,
                                                  const u16* __restrict__ Bh,
                                                  const u16* __restrict__ Bl,
                                                  float* __restrict__ P1) {
  constexpr int KLEN = 4096 / SPK;         // 256 @ SPK=16
  constexpr int STEPS = KLEN / 16;         // 16
  __shared__ u16 sAh[2][2][64][8];         // [abuf][rgrp][lane][8]  4 KB
  __shared__ u16 sAl[2][2][64][8];         // 4 KB
  __shared__ u16 sB[3][10][512];           // [bbuf][chunk ct*2+hl][1KB] 30 KB
  __shared__ u16 sScratch[512];            // dummy DMA target 1 KB
  const int t = threadIdx.x;
  const int lane = t & 63;
  const int w = t >> 6;
  const int rgrp = w & 1;
  const int cthalf = w >> 1;
  const int m0 = blockIdx.x * 64;
  const int sp = blockIdx.y;
  const int ct0 = cthalf ? 3 : 0;
  const int R = t >> 2;                    // staging row 0..63
  const int ksts = t & 3;                  // k-quad within step
  const int srg = R >> 5, srl = R & 31;
  const int skh = ksts >> 1, sj0 = (ksts & 1) * 4;

  f32x16 a0, a1, a2;
#pragma unroll
  for (int r = 0; r < 16; ++r) { a0[r] = 0.f; a1[r] = 0.f; a2[r] = 0.f; }

  const float* aptr = adj + (size_t)(m0 + R) * NN + sp * KLEN + ksts * 4;
  float4 va, vb, vc;                       // 3-deep A register sets

#define LOADA(it, tgt) tgt = *(const float4*)(aptr + (it) * 16);

#define CONV4(src, abuf)                                                       \
  {                                                                            \
    u16 h0, h1, h2, h3, l0, l1, l2, l3;                                        \
    split2(src.x, h0, l0); split2(src.y, h1, l1);                              \
    split2(src.z, h2, l2); split2(src.w, h3, l3);                              \
    ushort4_t hv = {h0, h1, h2, h3};                                           \
    ushort4_t lv = {l0, l1, l2, l3};                                           \
    *(ushort4_t*)&sAh[abuf][srg][srl + 32 * skh][sj0] = hv;                    \
    *(ushort4_t*)&sAl[abuf][srg][srl + 32 * skh][sj0] = lv;                    \
  }

#define BDMA(it, bbuf)                                                         \
  {                                                                            \
    _Pragma("unroll")                                                          \
    for (int j = 0; j < 3; ++j) {                                              \
      const int c = w + 4 * j;                                                 \
      const int ct = (c < 10) ? (c >> 1) : 0;                                  \
      const int hl = (c < 10) ? (c & 1) : 0;                                   \
      const int ks = sp * STEPS + (it);                                        \
      const u16* src =                                                         \
          (hl ? Bl : Bh) + (((size_t)ct * 256 + ks) * 64 + lane) * 8;          \
      gload_lds16(src, (c < 10) ? &sB[bbuf][c][0] : &sScratch[0]);             \
    }                                                                          \
  }

#define BAR(N)                                                                 \
  asm volatile("s_waitcnt vmcnt(" #N ") lgkmcnt(0)" ::: "memory");             \
  __builtin_amdgcn_sched_barrier(0);                                           \
  __builtin_amdgcn_s_barrier();                                                \
  __builtin_amdgcn_sched_barrier(0);

#define COMPUTE(abuf, bbuf)                                                    \
  {                                                                            \
    bf16x8 ah = *(const bf16x8*)&sAh[abuf][rgrp][lane][0];                     \
    bf16x8 al = *(const bf16x8*)&sAl[abuf][rgrp][lane][0];                     \
    const int cb = ct0 * 2;                                                    \
    bf16x8 b0h = *(const bf16x8*)&sB[bbuf][cb + 0][lane * 8];                  \
    bf16x8 b0l = *(const bf16x8*)&sB[bbuf][cb + 1][lane * 8];                  \
    bf16x8 b1h = *(const bf16x8*)&sB[bbuf][cb + 2][lane * 8];                  \
    bf16x8 b1l = *(const bf16x8*)&sB[bbuf][cb + 3][lane * 8];                  \
    a0 = __builtin_amdgcn_mfma_f32_32x32x16_bf16(ah, b0h, a0, 0, 0, 0);        \
    a1 = __builtin_amdgcn_mfma_f32_32x32x16_bf16(ah, b1h, a1, 0, 0, 0);        \
    a0 = __builtin_amdgcn_mfma_f32_32x32x16_bf16(al, b0h, a0, 0, 0, 0);        \
    a1 = __builtin_amdgcn_mfma_f32_32x32x16_bf16(al, b1h, a1, 0, 0, 0);        \
    a0 = __builtin_amdgcn_mfma_f32_32x32x16_bf16(ah, b0l, a0, 0, 0, 0);        \
    a1 = __builtin_amdgcn_mfma_f32_32x32x16_bf16(ah, b1l, a1, 0, 0, 0);        \
    if (cthalf == 0) {                                                         \
      bf16x8 b2h = *(const bf16x8*)&sB[bbuf][cb + 4][lane * 8];                \
      bf16x8 b2l = *(const bf16x8*)&sB[bbuf][cb + 5][lane * 8];                \
      a2 = __builtin_amdgcn_mfma_f32_32x32x16_bf16(ah, b2h, a2, 0, 0, 0);      \
      a2 = __builtin_amdgcn_mfma_f32_32x32x16_bf16(al, b2h, a2, 0, 0, 0);      \
      a2 = __builtin_amdgcn_mfma_f32_32x32x16_bf16(ah, b2l, a2, 0, 0, 0);      \
    }                                                                          \
  }

  // prologue: A0,A1,A2 in regs; B0,B1 DMA'd; convert A0; drain B0 only.
  LOADA(0, va);
  BDMA(0, 0);
  LOADA(1, vb);
  BDMA(1, 1);
  LOADA(2, vc);
  CONV4(va, 0);
  BAR(5)   // retire B0 (3); keep vb, B1(3), vc
#pragma unroll
  for (int it = 0; it < STEPS; ++it) {
    const int abuf = it & 1;
    const int bbuf = it % 3;
    if (it < STEPS - 2) BDMA(it + 2, (it + 2) % 3);
    if (it <= STEPS - 4) {
      if ((it % 3) == 0) { LOADA(it + 3, va); }
      else if ((it % 3) == 1) { LOADA(it + 3, vb); }
      else { LOADA(it + 3, vc); }
    }
    COMPUTE(abuf, bbuf);
    if (it < STEPS - 1) {
      if (((it + 1) % 3) == 0) { CONV4(va, abuf ^ 1); }
      else if (((it + 1) % 3) == 1) { CONV4(vb, abuf ^ 1); }
      else { CONV4(vc, abuf ^ 1); }
    }
    if (it <= STEPS - 4) { BAR(5) }
    else if (it == STEPS - 3) { BAR(4) }
    else if (it == STEPS - 2) { BAR(0) }
  }
#undef LOADA
#undef CONV4
#undef BDMA
#undef BAR
#undef COMPUTE
  // epilogue: C/D layout col=lane&31, row=(r&3)+8*(r>>2)+4*(lane>>5)
  float* outp = P1 + (size_t)sp * NN * CST;
  const int colb = lane & 31;
  const int rbase = m0 + rgrp * 32 + 4 * (lane >> 5);
  {
    const int colg = ct0 * 32 + colb;
#pragma unroll
    for (int r = 0; r < 16; ++r)
      outp[(size_t)(rbase + (r & 3) + 8 * (r >> 2)) * CST + colg] = a0[r];
  }
  {
    const int colg = (ct0 + 1) * 32 + colb;
    if (colg < CST) {
#pragma unroll
      for (int r = 0; r < 16; ++r)
        outp[(size_t)(rbase + (r & 3) + 8 * (r >> 2)) * CST + colg] = a1[r];
    }
  }
  if (cthalf == 0) {
    const int colg = 64 + colb;
#pragma unroll
    for (int r = 0; r < 16; ++r)
      outp[(size_t)(rbase + (r & 3) + 8 * (r >> 2)) * CST + colg] = a2[r];
  }
}

// ---------------- K23: fused P1-reduce + r,u + h2 + cand + out --------------
// grid (128, 2): x = 32-node block, y = own output ct half.
// Phase 1 computes r(ct=0), r(ct=1), u(own ct) in ONE fused MFMA pass
// (3 accumulator chains, 6 outstanding W loads per K-step), exchanged in a
// single 96 KB sXfer round. Phase 2 = cand (3-chain ILP). 6 syncthreads.

#define PACKA()                                                                \
  for (int s = t; s < 9 * 64; s += 512) {                                      \
    int kst = s >> 6, l = s & 63;                                              \
    int row = l & 31, k0i = kst * 16 + (l >> 5) * 8;                           \
    ushort8_t vh, vl;                                                          \
    _Pragma("unroll")                                                          \
    for (int j = 0; j < 8; ++j) {                                              \
      u16 hi, lo; split2(sXV[row][k0i + j], hi, lo);                           \
      vh[j] = hi; vl[j] = lo;                                                  \
    }                                                                          \
    *(ushort8_t*)&sAh[kst * AKST + l * 8] = vh;                                \
    *(ushort8_t*)&sAl[kst * AKST + l * 8] = vl;                                \
  }

template <int SPK>
__global__ __launch_bounds__(512) void k23_fused(
    const float* __restrict__ P1, const float* __restrict__ x,
    const float* __restrict__ h, const float* __restrict__ q,
    const u16* __restrict__ Wh, const u16* __restrict__ Wl,
    const float* __restrict__ br, const float* __restrict__ bu,
    const float* __restrict__ bc, float* __restrict__ out) {
  __shared__ float sXV[32][XVST];
  __shared__ u16 sAh[9 * AKST], sAl[9 * AKST];
  __shared__ float sQ[32][16];
  __shared__ float sX0[8][16][64];   // r ct=0 partials
  __shared__ float sX1[8][16][64];   // r ct=1 partials
  __shared__ float sX2[8][16][64];   // u partials (cand reuses sX0)
  const int t = threadIdx.x;
  const int n0 = blockIdx.x * 32;
  const int cto = blockIdx.y;
  // --- split-K reduce of P1 directly into sXV ---
  for (int f = t; f < 32 * 33; f += 512) {
    int n = f / 33, c4 = f - n * 33;
    const float* p = P1 + (size_t)(n0 + n) * CST + c4 * 4;
    float sx = 0.f, sy = 0.f, sz = 0.f, sw = 0.f;
#pragma unroll
    for (int sp = 0; sp < SPK; ++sp) {
      float4 v = *(const float4*)(p + (size_t)sp * NN * CST);
      sx += v.x; sy += v.y; sz += v.z; sw += v.w;
    }
    sXV[n][c4 * 4 + 0] = sx; sXV[n][c4 * 4 + 1] = sy;
    sXV[n][c4 * 4 + 2] = sz; sXV[n][c4 * 4 + 3] = sw;
  }
  for (int f = t; f < 32 * 3; f += 512) {
    float4 z = {0, 0, 0, 0};
    *(float4*)&sXV[f / 3][132 + (f % 3) * 4] = z;
  }
  sQ[t >> 4][t & 15] = q[(size_t)(n0 + (t >> 4)) * QDIM + (t & 15)];
  __syncthreads();                                   // (1)
  PACKA();
  __syncthreads();                                   // (2)
  // stage x into sXV[.][0..64] now (consumed only by PACKA#2, two barriers
  // away); hides the global latency under the phase-1 MFMAs.
  for (int f = t; f < 32 * 65; f += 512) {
    int n = f / 65, i = f - n * 65;
    sXV[n][i] = x[(size_t)(n0 + n) * XCC + i];
  }
  const int lane = t & 63, dh = t >> 6;

  // ---- phase 1: fused r(ct0), r(ct1), u(own) ----
  f32x16 aR0, aR1, aU;
#pragma unroll
  for (int r = 0; r < 16; ++r) { aR0[r] = 0.f; aR1[r] = 0.f; aU[r] = 0.f; }
#pragma unroll
  for (int dd = 0; dd < 2; ++dd) {
    const int d = dh * 2 + dd;
    const size_t bR0 = (((size_t)d * 2 + 0) * 9 * 64 + lane) * 8;
    const size_t bR1 = (((size_t)d * 2 + 1) * 9 * 64 + lane) * 8;
    const size_t bU  = (((size_t)d * 2 + cto) * 9 * 64 + lane) * 8 + GSTRIDE;
    f32x16 t0, t1, t2;
#pragma unroll
    for (int r = 0; r < 16; ++r) { t0[r] = 0.f; t1[r] = 0.f; t2[r] = 0.f; }
#pragma unroll
    for (int kst = 0; kst < 9; ++kst) {
      bf16x8 ah = *(const bf16x8*)&sAh[kst * AKST + lane * 8];
      bf16x8 al = *(const bf16x8*)&sAl[kst * AKST + lane * 8];
      bf16x8 b0h = *(const bf16x8*)(Wh + bR0 + kst * 512);
      bf16x8 b0l = *(const bf16x8*)(Wl + bR0 + kst * 512);
      bf16x8 b1h = *(const bf16x8*)(Wh + bR1 + kst * 512);
      bf16x8 b1l = *(const bf16x8*)(Wl + bR1 + kst * 512);
      bf16x8 buh = *(const bf16x8*)(Wh + bU + kst * 512);
      bf16x8 bul = *(const bf16x8*)(Wl + bU + kst * 512);
      t0 = __builtin_amdgcn_mfma_f32_32x32x16_bf16(ah, b0h, t0, 0, 0, 0);
      t1 = __builtin_amdgcn_mfma_f32_32x32x16_bf16(ah, b1h, t1, 0, 0, 0);
      t2 = __builtin_amdgcn_mfma_f32_32x32x16_bf16(ah, buh, t2, 0, 0, 0);
      t0 = __builtin_amdgcn_mfma_f32_32x32x16_bf16(al, b0h, t0, 0, 0, 0);
      t1 = __builtin_amdgcn_mfma_f32_32x32x16_bf16(al, b1h, t1, 0, 0, 0);
      t2 = __builtin_amdgcn_mfma_f32_32x32x16_bf16(al, buh, t2, 0, 0, 0);
      t0 = __builtin_amdgcn_mfma_f32_32x32x16_bf16(ah, b0l, t0, 0, 0, 0);
      t1 = __builtin_amdgcn_mfma_f32_32x32x16_bf16(ah, b1l, t1, 0, 0, 0);
      t2 = __builtin_amdgcn_mfma_f32_32x32x16_bf16(ah, bul, t2, 0, 0, 0);
    }
#pragma unroll
    for (int r = 0; r < 16; ++r) {
      int node = (r & 3) + 8 * (r >> 2) + 4 * (lane >> 5);
      float qd = sQ[node][d];
      aR0[r] += qd * t0[r]; aR1[r] += qd * t1[r]; aU[r] += qd * t2[r];
    }
  }
  // first-ever sXfer use: no pre-sync needed
#pragma unroll
  for (int r = 0; r < 16; ++r) {
    sX0[dh][r][lane] = aR0[r];
    sX1[dh][r][lane] = aR1[r];
    sX2[dh][r][lane] = aU[r];
  }
  __syncthreads();                                   // (3)

  auto add_bias = [&](const float* bias, int node, int col, float pre) {
#pragma unroll
    for (int d = 0; d < 16; ++d) pre += sQ[node][d] * bias[(size_t)d * 64 + col];
    return pre;
  };

  float r0p[2], r1p[2], up[2];
#pragma unroll
  for (int i = 0; i < 2; ++i) {
    const int rr = dh * 2 + i;
    float a = 0.f, b = 0.f, c = 0.f;
#pragma unroll
    for (int wv = 0; wv < 8; ++wv) {
      a += sX0[wv][rr][lane];
      b += sX1[wv][rr][lane];
      c += sX2[wv][rr][lane];
    }
    r0p[i] = a; r1p[i] = b; up[i] = c;
  }

  const int col0 = lane & 31, col1 = 32 + col0, colu = cto * 32 + col0;
  float uval[2], h2own[2];
#pragma unroll
  for (int i = 0; i < 2; ++i) {
    const int rr = dh * 2 + i;
    const int node = (rr & 3) + 8 * (rr >> 2) + 4 * (lane >> 5);
    float pr0 = add_bias(br, node, col0, r0p[i]);
    float pr1 = add_bias(br, node, col1, r1p[i]);
    float pu  = add_bias(bu, node, colu, up[i]);
    float rg0 = 1.f / (1.f + expf(-pr0));
    float rg1 = 1.f / (1.f + expf(-pr1));
    uval[i] = 1.f / (1.f + expf(-pu));
    float h2a = rg0 * h[(size_t)(n0 + node) * HCC + col0];
    float h2b = rg1 * h[(size_t)(n0 + node) * HCC + col1];
    sXV[node][XCC + col0] = h2a;   // build full h2 row locally
    sXV[node][XCC + col1] = h2b;
    h2own[i] = cto ? h2b : h2a;
  }
  __syncthreads();                                   // (4) h2 + x visible
  PACKA();                                           // A = [x | h2]
  __syncthreads();                                   // (5)

  // ---- phase 2: cand (own ct), 3-chain ILP ----
  {
    const u16* gh = Wh + (size_t)2 * GSTRIDE;
    const u16* gl = Wl + (size_t)2 * GSTRIDE;
    f32x16 acc;
#pragma unroll
    for (int r = 0; r < 16; ++r) acc[r] = 0.f;
#pragma unroll
    for (int dd = 0; dd < 2; ++dd) {
      const int d = dh * 2 + dd;
      const size_t bb = (((size_t)d * 2 + cto) * 9 * 64 + lane) * 8;
      f32x16 t0, t1, t2;
#pragma unroll
      for (int r = 0; r < 16; ++r) { t0[r] = 0.f; t1[r] = 0.f; t2[r] = 0.f; }
#pragma unroll
      for (int kst = 0; kst < 9; ++kst) {
        bf16x8 ah = *(const bf16x8*)&sAh[kst * AKST + lane * 8];
        bf16x8 al = *(const bf16x8*)&sAl[kst * AKST + lane * 8];
        bf16x8 bh = *(const bf16x8*)(gh + bb + kst * 512);
        bf16x8 bl = *(const bf16x8*)(gl + bb + kst * 512);
        t0 = __builtin_amdgcn_mfma_f32_32x32x16_bf16(ah, bh, t0, 0, 0, 0);
        t1 = __builtin_amdgcn_mfma_f32_32x32x16_bf16(al, bh, t1, 0, 0, 0);
        t2 = __builtin_amdgcn_mfma_f32_32x32x16_bf16(ah, bl, t2, 0, 0, 0);
      }
#pragma unroll
      for (int r = 0; r < 16; ++r) {
        int node = (r & 3) + 8 * (r >> 2) + 4 * (lane >> 5);
        acc[r] += sQ[node][d] * (t0[r] + t1[r] + t2[r]);
      }
    }
    // sX0 last read was before barriers (4)/(5): safe to overwrite
#pragma unroll
    for (int r = 0; r < 16; ++r) sX0[dh][r][lane] = acc[r];
  }
  __syncthreads();                                   // (6)
#pragma unroll
  for (int i = 0; i < 2; ++i) {
    const int rr = dh * 2 + i;
    const int node = (rr & 3) + 8 * (rr >> 2) + 4 * (lane >> 5);
    float s = 0.f;
#pragma unroll
    for (int wv = 0; wv < 8; ++wv) s += sX0[wv][rr][lane];
    float pc = add_bias(bc, node, colu, s);
    float cand = tanhf(pc);
    out[(size_t)(n0 + node) * HCC + colu] =
        (1.f - uval[i]) * h2own[i] + uval[i] * cand;
  }
}

extern "C" void kernel_launch(void* const* d_in, const int* in_sizes, int n_in,
                              void* d_out, int out_size, void* d_ws, size_t ws_size,
                              hipStream_t stream) {
  const float* x   = (const float*)d_in[0];
  const float* h   = (const float*)d_in[1];
  const float* q   = (const float*)d_in[2];
  const float* adj = (const float*)d_in[3];
  const float* Wr  = (const float*)d_in[5];
  const float* br  = (const float*)d_in[6];
  const float* Wu  = (const float*)d_in[7];
  const float* bu  = (const float*)d_in[8];
  const float* Wc  = (const float*)d_in[9];
  const float* bc  = (const float*)d_in[10];
  float* out = (float*)d_out;

  const size_t NEED16 = (size_t)16 * NN * CST * 4 + 2162688 + 10485760 + 1769472;
  const int spk = (ws_size >= NEED16) ? 16 : 8;

  char* ws = (char*)d_ws;
  const size_t OFF_P1 = 0;
  const size_t OFF_XV = OFF_P1 + (size_t)spk * NN * CST * 4;  // region kept for layout
  const size_t OFF_BP = OFF_XV + (size_t)NN * CST * 4;
  const size_t OFF_WH = OFF_BP + (size_t)2 * 5 * 256 * 64 * 8 * 2;
  const size_t OFF_WL = OFF_WH + (size_t)3 * GSTRIDE * 2;
  float* P1 = (float*)(ws + OFF_P1);
  u16*   Bh = (u16*)(ws + OFF_BP);
  u16*   Bl = (u16*)(ws + OFF_BP + (size_t)5 * 256 * 64 * 8 * 2);
  u16*   Wh = (u16*)(ws + OFF_WH);
  u16*   Wl = (u16*)(ws + OFF_WL);

  hipLaunchKernelGGL(k0_pack, dim3(280), dim3(256), 0, stream,
                     x, h, Bh, Bl, Wr, Wu, Wc, Wh, Wl);
  if (spk == 16) {
    hipLaunchKernelGGL(k1_mfma<16>, dim3(64, 16), dim3(256), 0, stream, adj, Bh, Bl, P1);
    hipLaunchKernelGGL(k23_fused<16>, dim3(128, 2), dim3(512), 0, stream,
                       P1, x, h, q, Wh, Wl, br, bu, bc, out);
  } else {
    hipLaunchKernelGGL(k1_mfma<8>, dim3(64, 8), dim3(256), 0, stream, adj, Bh, Bl, P1);
    hipLaunchKernelGGL(k23_fused<8>, dim3(128, 2), dim3(512), 0, stream,
                       P1, x, h, q, Wh, Wl, br, bu, bc, out);
  }
}